// Round 1
// baseline (537.980 us; speedup 1.0000x reference)
//
#include <hip/hip_runtime.h>
#include <math.h>

// N=8192 tokens, D=1024. All inputs fp32. Internally bf16 MFMA.
// out = (E@g)/l + gate*colsum(g) + x, E = exp(c * (q-uq)@(k-uk)^T), l = rowsum(E)

#define NT 8192
#define DD 1024

typedef float v4f __attribute__((ext_vector_type(4)));
typedef short v8s __attribute__((ext_vector_type(8)));

typedef const __attribute__((address_space(1))) void* gp_t;
typedef __attribute__((address_space(3))) void* lp_t;

__device__ __forceinline__ short f2b(float f) {
    unsigned u = __float_as_uint(f);
    return (short)((u + 0x7fffu + ((u >> 16) & 1u)) >> 16);   // RNE
}
__device__ __forceinline__ float b2f(short s) {
    return __uint_as_float(((unsigned)(unsigned short)s) << 16);
}

// supertile swizzle: bands of 16 row-tiles so concurrent blocks share A/B panels in L2/LLC
__device__ __forceinline__ void tile_coords(int bid, int tn, int& bm, int& bn) {
    const int SUP = 16;
    int per = SUP * tn;
    int band = bid / per, r = bid % per;
    bm = band * SUP + (r % SUP);
    bn = r / SUP;
}

// ---------------- GEMM core ----------------
// A: [M x K] bf16 row-major, B: [N x K] bf16 row-major (i.e. B^T input).
// C tile 128x128 at (m0,n0): 256 threads, 4 waves 2x2, each wave 4x4 of 16x16x32 MFMA.
// BK=64. LDS tiles XOR-swizzled: logical 16B chunk g of row r stored at phys chunk g^(r&7)
// -> staging via global_load_lds stays wave-uniform-base contiguous (permute GLOBAL addr),
//    ds_read_b128 is 2-way-conflict-free (free per m136).
__device__ __forceinline__ void gemm_core(const short* __restrict__ A,
                                          const short* __restrict__ B,
                                          int K, int m0, int n0,
                                          short* smem, v4f (&acc)[4][4])
{
    short* lsA = smem;            // 128*64 shorts
    short* lsB = smem + 8192;     // 128*64 shorts
    const int tid  = threadIdx.x;
    const int wave = tid >> 6, lane = tid & 63;
    const int l15 = lane & 15, l4 = lane >> 4;
    const int wm = (wave >> 1) << 6, wn = (wave & 1) << 6;

#pragma unroll
    for (int i = 0; i < 4; i++)
#pragma unroll
        for (int j = 0; j < 4; j++) acc[i][j] = (v4f)(0.0f);

    const int srow = lane >> 3;          // row within 8-row issue group
    const int g    = (lane & 7) ^ srow;  // logical 16B chunk for this lane (swizzle)

    for (int k0 = 0; k0 < K; k0 += 64) {
#pragma unroll
        for (int i = 0; i < 4; i++) {
            int ci  = wave * 4 + i;          // 16 chunks of 1KB per 16KB tile
            int row = ci * 8 + srow;
            const short* ga = A + (size_t)(m0 + row) * K + k0 + g * 8;
            const short* gb = B + (size_t)(n0 + row) * K + k0 + g * 8;
            __builtin_amdgcn_global_load_lds((gp_t)ga, (lp_t)(lsA + ci * 512), 16, 0, 0);
            __builtin_amdgcn_global_load_lds((gp_t)gb, (lp_t)(lsB + ci * 512), 16, 0, 0);
        }
        __syncthreads();
#pragma unroll
        for (int kk = 0; kk < 64; kk += 32) {
            v8s af[4], bf[4];
#pragma unroll
            for (int t = 0; t < 4; t++) {
                int ra = wm + t * 16 + l15;
                int ca = ((kk >> 3) + l4) ^ (ra & 7);
                af[t] = *(const v8s*)(lsA + ra * 64 + ca * 8);
                int rb = wn + t * 16 + l15;
                int cb = ((kk >> 3) + l4) ^ (rb & 7);
                bf[t] = *(const v8s*)(lsB + rb * 64 + cb * 8);
            }
#pragma unroll
            for (int i = 0; i < 4; i++)
#pragma unroll
                for (int j = 0; j < 4; j++)
                    acc[i][j] = __builtin_amdgcn_mfma_f32_16x16x32_bf16(af[i], bf[j], acc[i][j], 0, 0, 0);
        }
        __syncthreads();
    }
}

// ---------------- small kernels ----------------

__global__ void cvt_x(const float* __restrict__ x, short* __restrict__ xb) {
    size_t i = ((size_t)blockIdx.x * 256 + threadIdx.x) * 8;
    float4 a = *(const float4*)(x + i);
    float4 b = *(const float4*)(x + i + 4);
    v8s o;
    o[0] = f2b(a.x); o[1] = f2b(a.y); o[2] = f2b(a.z); o[3] = f2b(a.w);
    o[4] = f2b(b.x); o[5] = f2b(b.y); o[6] = f2b(b.z); o[7] = f2b(b.w);
    *(v8s*)(xb + i) = o;
}

// transpose+convert weights: wbt[n][k] = W*(k, n%1024), n fused over {Wq,Wk,Wg}
__global__ void cvt_w(const float* __restrict__ Wq, const float* __restrict__ Wk,
                      const float* __restrict__ Wg, short* __restrict__ wbt) {
    __shared__ float t[64][68];
    const float* W = blockIdx.z == 0 ? Wq : (blockIdx.z == 1 ? Wk : Wg);
    int k0 = blockIdx.x * 64, n0 = blockIdx.y * 64;
    int tr = threadIdx.x >> 4, tc = threadIdx.x & 15;
#pragma unroll
    for (int p = 0; p < 4; p++) {
        int r = p * 16 + tr;
        float4 v = *(const float4*)(W + (size_t)(k0 + r) * DD + n0 + tc * 4);
        t[r][tc * 4 + 0] = v.x; t[r][tc * 4 + 1] = v.y;
        t[r][tc * 4 + 2] = v.z; t[r][tc * 4 + 3] = v.w;
    }
    __syncthreads();
#pragma unroll
    for (int p = 0; p < 4; p++) {
        int rr = p * 16 + tr;   // local n
        short4 s;
        s.x = f2b(t[tc * 4 + 0][rr]); s.y = f2b(t[tc * 4 + 1][rr]);
        s.z = f2b(t[tc * 4 + 2][rr]); s.w = f2b(t[tc * 4 + 3][rr]);
        *(short4*)(wbt + (size_t)(blockIdx.z * DD + n0 + rr) * DD + k0 + tc * 4) = s;
    }
}

// m[i] = x[i,:] . Wm_w + b   (one wave per row)
__global__ void gemv_m(const float* __restrict__ x, const float* __restrict__ wv,
                       const float* __restrict__ bp, float* __restrict__ mout) {
    int row = blockIdx.x * 4 + (threadIdx.x >> 6);
    int lane = threadIdx.x & 63;
    const float* xr = x + (size_t)row * DD;
    float s = 0.f;
    for (int c = lane * 4; c < DD; c += 256) {
        float4 a = *(const float4*)(xr + c);
        float4 b = *(const float4*)(wv + c);
        s = fmaf(a.x, b.x, s); s = fmaf(a.y, b.y, s);
        s = fmaf(a.z, b.z, s); s = fmaf(a.w, b.w, s);
    }
    for (int o = 32; o; o >>= 1) s += __shfl_down(s, o);
    if (lane == 0) mout[row] = s + bp[0];
}

// gate = softmax(m) over all 8192 tokens (single block)
__global__ void gate_k(const float* __restrict__ m, float* __restrict__ gate) {
    __shared__ float sred[4];
    __shared__ float sbc[2];
    int tid = threadIdx.x, lane = tid & 63, wave = tid >> 6;
    float mx = -3.4e38f;
    for (int i = tid; i < NT; i += 256) mx = fmaxf(mx, m[i]);
    for (int o = 32; o; o >>= 1) mx = fmaxf(mx, __shfl_xor(mx, o));
    if (lane == 0) sred[wave] = mx;
    __syncthreads();
    if (tid == 0) sbc[0] = fmaxf(fmaxf(sred[0], sred[1]), fmaxf(sred[2], sred[3]));
    __syncthreads();
    float gmax = sbc[0];
    float s = 0.f;
    for (int i = tid; i < NT; i += 256) s += expf(m[i] - gmax);
    for (int o = 32; o; o >>= 1) s += __shfl_xor(s, o);
    if (lane == 0) sred[wave] = s;
    __syncthreads();
    if (tid == 0) sbc[1] = sred[0] + sred[1] + sred[2] + sred[3];
    __syncthreads();
    float inv = 1.f / sbc[1];
    for (int i = tid; i < NT; i += 256) gate[i] = expf(m[i] - gmax) * inv;
}

// q/k -= column mean (in-place on bf16 buffers)
__global__ void center_qk(short* __restrict__ qb, short* __restrict__ kb,
                          const float* __restrict__ qs, const float* __restrict__ ks) {
    size_t idx = ((size_t)blockIdx.x * 256 + threadIdx.x) * 8;
    int col = (int)(idx & (DD - 1));
    v8s vq = *(v8s*)(qb + idx);
    v8s vk = *(v8s*)(kb + idx);
    const float scale = 1.f / (float)NT;
#pragma unroll
    for (int j = 0; j < 8; j++) {
        vq[j] = f2b(b2f(vq[j]) - qs[col + j] * scale);
        vk[j] = f2b(b2f(vk[j]) - ks[col + j] * scale);
    }
    *(v8s*)(qb + idx) = vq;
    *(v8s*)(kb + idx) = vk;
}

// ---------------- GEMM kernels ----------------

// K1: C = x @ [Wq|Wk|Wg]  (M=8192, N=3072, K=1024)
__global__ __launch_bounds__(256, 2) void k_proj(
        const short* __restrict__ xb, const short* __restrict__ wbt,
        short* __restrict__ qb, short* __restrict__ kb, short* __restrict__ gbt,
        float* __restrict__ qsum, float* __restrict__ ksum, float* __restrict__ gsum) {
    __shared__ __align__(16) short smem[17408];   // 16384 staging, 17408 for transpose
    int bm, bn; tile_coords(blockIdx.x, 24, bm, bn);
    int m0 = bm * 128, n0 = bn * 128;
    v4f acc[4][4];
    gemm_core(xb, wbt, DD, m0, n0, smem, acc);

    const int tid = threadIdx.x, wave = tid >> 6, lane = tid & 63;
    const int l15 = lane & 15, l4 = lane >> 4;
    const int wm = (wave >> 1) << 6, wn = (wave & 1) << 6;
    int sec = n0 >> 10;            // 0=q 1=k 2=g
    int nloc = n0 & (DD - 1);

    if (sec < 2) {
        short* dst  = sec ? kb : qb;
        float* sums = sec ? ksum : qsum;
        float cs[4] = {0.f, 0.f, 0.f, 0.f};
#pragma unroll
        for (int i = 0; i < 4; i++)
#pragma unroll
            for (int j = 0; j < 4; j++)
#pragma unroll
                for (int v = 0; v < 4; v++) {
                    int row = m0 + wm + i * 16 + l4 * 4 + v;
                    int col = nloc + wn + j * 16 + l15;
                    dst[(size_t)row * DD + col] = f2b(acc[i][j][v]);
                    cs[j] += acc[i][j][v];
                }
#pragma unroll
        for (int j = 0; j < 4; j++)
            atomicAdd(&sums[nloc + wn + j * 16 + l15], cs[j]);
    } else {
        // g tile -> transposed store gbt[d][i] via LDS bounce (stride 136 breaks conflicts)
        float cs[4] = {0.f, 0.f, 0.f, 0.f};
#pragma unroll
        for (int i = 0; i < 4; i++)
#pragma unroll
            for (int j = 0; j < 4; j++)
#pragma unroll
                for (int v = 0; v < 4; v++) {
                    int lr = wn + j * 16 + l15;            // local d
                    int lc = wm + i * 16 + l4 * 4 + v;     // local token
                    smem[lr * 136 + lc] = f2b(acc[i][j][v]);
                    cs[j] += acc[i][j][v];
                }
        __syncthreads();
#pragma unroll
        for (int it = 0; it < 8; it++) {
            int c = it * 256 + tid;          // 2048 chunks of 8 shorts
            int dr = c >> 4, cm = (c & 15) * 8;
            v8s vv = *(const v8s*)(smem + dr * 136 + cm);
            *(v8s*)(gbt + (size_t)(nloc + dr) * NT + m0 + cm) = vv;
        }
#pragma unroll
        for (int j = 0; j < 4; j++)
            atomicAdd(&gsum[nloc + wn + j * 16 + l15], cs[j]);
    }
}

// K3: E = exp(c * q@k^T) bf16, l += rowsum(E)   (M=N=8192, K=1024)
__global__ __launch_bounds__(256, 2) void k_score(
        const short* __restrict__ qb, const short* __restrict__ kb,
        short* __restrict__ E, float* __restrict__ l, const float* __restrict__ cptr) {
    __shared__ __align__(16) short smem[16384];
    int bm, bn; tile_coords(blockIdx.x, 64, bm, bn);
    int m0 = bm * 128, n0 = bn * 128;
    v4f acc[4][4];
    gemm_core(qb, kb, DD, m0, n0, smem, acc);

    const float cv = cptr[0];
    const int tid = threadIdx.x, wave = tid >> 6, lane = tid & 63;
    const int l15 = lane & 15, l4 = lane >> 4;
    const int wm = (wave >> 1) << 6, wn = (wave & 1) << 6;
#pragma unroll
    for (int i = 0; i < 4; i++)
#pragma unroll
        for (int v = 0; v < 4; v++) {
            int row = m0 + wm + i * 16 + l4 * 4 + v;
            float rsum = 0.f;
#pragma unroll
            for (int j = 0; j < 4; j++) {
                float e = __expf(cv * acc[i][j][v]);
                E[(size_t)row * NT + (n0 + wn + j * 16 + l15)] = f2b(e);
                rsum += e;
            }
#pragma unroll
            for (int o = 1; o < 16; o <<= 1) rsum += __shfl_xor(rsum, o);
            if (l15 == 0) atomicAdd(&l[row], rsum);
        }
}

// K4: out = (E @ g)/l + gate*gsum + x   (M=8192, N=1024, K=8192)
__global__ __launch_bounds__(256, 2) void k_out(
        const short* __restrict__ E, const short* __restrict__ gbt,
        const float* __restrict__ l, const float* __restrict__ gate,
        const float* __restrict__ gsum, const float* __restrict__ x,
        float* __restrict__ out) {
    __shared__ __align__(16) short smem[16384];
    int bm, bn; tile_coords(blockIdx.x, 8, bm, bn);
    int m0 = bm * 128, n0 = bn * 128;
    v4f acc[4][4];
    gemm_core(E, gbt, NT, m0, n0, smem, acc);

    const int tid = threadIdx.x, wave = tid >> 6, lane = tid & 63;
    const int l15 = lane & 15, l4 = lane >> 4;
    const int wm = (wave >> 1) << 6, wn = (wave & 1) << 6;
#pragma unroll
    for (int i = 0; i < 4; i++)
#pragma unroll
        for (int v = 0; v < 4; v++) {
            int row = m0 + wm + i * 16 + l4 * 4 + v;
            float inv = 1.f / l[row];
            float gv  = gate[row];
#pragma unroll
            for (int j = 0; j < 4; j++) {
                int col = n0 + wn + j * 16 + l15;
                out[(size_t)row * DD + col] =
                    acc[i][j][v] * inv + gv * gsum[col] + x[(size_t)row * DD + col];
            }
        }
}

// ---------------- launch ----------------

extern "C" void kernel_launch(void* const* d_in, const int* in_sizes, int n_in,
                              void* d_out, int out_size, void* d_ws, size_t ws_size,
                              hipStream_t stream) {
    const float* x  = (const float*)d_in[0];
    const float* Wq = (const float*)d_in[1];
    const float* Wk = (const float*)d_in[2];
    const float* Wg = (const float*)d_in[3];
    const float* Wm = (const float*)d_in[4];
    const float* Wb = (const float*)d_in[5];
    const float* cp = (const float*)d_in[6];
    float* out = (float*)d_out;

    char* w = (char*)d_ws;
    size_t off = 0;
    auto alloc = [&](size_t bytes) -> void* {
        void* p = w + off;
        off += (bytes + 255) & ~(size_t)255;
        return p;
    };
    short* qb    = (short*)alloc((size_t)NT * DD * 2);      // 16 MB
    short* kb    = (short*)alloc((size_t)NT * DD * 2);      // 16 MB
    short* gbt   = (short*)alloc((size_t)DD * NT * 2);      // 16 MB (transposed g)
    short* wbt   = (short*)alloc((size_t)3 * DD * DD * 2);  // 6 MB
    short* xb    = (short*)alloc((size_t)NT * DD * 2);      // 16 MB
    short* E     = (short*)alloc((size_t)NT * NT * 2);      // 128 MB
    float* stats = (float*)alloc((3 * DD + 3 * NT) * 4);
    float* qsum = stats;
    float* ksum = stats + DD;
    float* gsum = stats + 2 * DD;
    float* lrow = stats + 3 * DD;
    float* mvec = lrow + NT;
    float* gate = mvec + NT;
    if (off > ws_size) return;   // workspace too small: bail cleanly (diagnosable)

    // zero qsum/ksum/gsum/l (contiguous)
    hipMemsetAsync(stats, 0, (size_t)(3 * DD + NT) * 4, stream);

    cvt_x<<<NT * DD / (256 * 8), 256, 0, stream>>>(x, xb);
    cvt_w<<<dim3(16, 16, 3), 256, 0, stream>>>(Wq, Wk, Wg, wbt);
    gemv_m<<<NT / 4, 256, 0, stream>>>(x, Wm, Wb, mvec);
    gate_k<<<1, 256, 0, stream>>>(mvec, gate);
    k_proj<<<64 * 24, 256, 0, stream>>>(xb, wbt, qb, kb, gbt, qsum, ksum, gsum);
    center_qk<<<NT * DD / (256 * 8), 256, 0, stream>>>(qb, kb, qsum, ksum);
    k_score<<<64 * 64, 256, 0, stream>>>(qb, kb, E, lrow, cp);
    k_out<<<64 * 8, 256, 0, stream>>>(E, gbt, lrow, gate, gsum, x, out);
}

// Round 2
// 469.231 us; speedup vs baseline: 1.1465x; 1.1465x over previous
//
#include <hip/hip_runtime.h>
#include <math.h>

// N=8192 tokens, D=1024. All inputs fp32.
// out = (E@g)/l + gate*colsum(g) + x, E = exp(c * (q-uq)@(k-uk)^T), l = rowsum(E)
// R2: score + PV GEMMs in fp8-e4m3 (q,k,g,E); projection GEMM stays bf16.

#define NT 8192
#define DD 1024

typedef float v4f __attribute__((ext_vector_type(4)));
typedef short v8s __attribute__((ext_vector_type(8)));

typedef const __attribute__((address_space(1))) void* gp_t;
typedef __attribute__((address_space(3))) void* lp_t;

__device__ __forceinline__ short f2b(float f) {
    unsigned u = __float_as_uint(f);
    return (short)((u + 0x7fffu + ((u >> 16) & 1u)) >> 16);   // RNE
}
__device__ __forceinline__ float b2f(short s) {
    return __uint_as_float(((unsigned)(unsigned short)s) << 16);
}
__device__ __forceinline__ char f2e4m3(float f) {
    unsigned p = __builtin_amdgcn_cvt_pk_fp8_f32(f, f, 0, false);
    return (char)(p & 0xff);
}

// supertile swizzle: bands of 16 row-tiles so concurrent blocks share A/B panels in L2/LLC
__device__ __forceinline__ void tile_coords(int bid, int tn, int& bm, int& bn) {
    const int SUP = 16;
    int per = SUP * tn;
    int band = bid / per, r = bid % per;
    bm = band * SUP + (r % SUP);
    bn = r / SUP;
}

// ---------------- bf16 GEMM core (unchanged from R1) ----------------
__device__ __forceinline__ void gemm_core(const short* __restrict__ A,
                                          const short* __restrict__ B,
                                          int K, int m0, int n0,
                                          short* smem, v4f (&acc)[4][4])
{
    short* lsA = smem;            // 128*64 shorts
    short* lsB = smem + 8192;     // 128*64 shorts
    const int tid  = threadIdx.x;
    const int wave = tid >> 6, lane = tid & 63;
    const int l15 = lane & 15, l4 = lane >> 4;
    const int wm = (wave >> 1) << 6, wn = (wave & 1) << 6;

#pragma unroll
    for (int i = 0; i < 4; i++)
#pragma unroll
        for (int j = 0; j < 4; j++) acc[i][j] = (v4f)(0.0f);

    const int srow = lane >> 3;
    const int g    = (lane & 7) ^ srow;

    for (int k0 = 0; k0 < K; k0 += 64) {
#pragma unroll
        for (int i = 0; i < 4; i++) {
            int ci  = wave * 4 + i;
            int row = ci * 8 + srow;
            const short* ga = A + (size_t)(m0 + row) * K + k0 + g * 8;
            const short* gb = B + (size_t)(n0 + row) * K + k0 + g * 8;
            __builtin_amdgcn_global_load_lds((gp_t)ga, (lp_t)(lsA + ci * 512), 16, 0, 0);
            __builtin_amdgcn_global_load_lds((gp_t)gb, (lp_t)(lsB + ci * 512), 16, 0, 0);
        }
        __syncthreads();
#pragma unroll
        for (int kk = 0; kk < 64; kk += 32) {
            v8s af[4], bf[4];
#pragma unroll
            for (int t = 0; t < 4; t++) {
                int ra = wm + t * 16 + l15;
                int ca = ((kk >> 3) + l4) ^ (ra & 7);
                af[t] = *(const v8s*)(lsA + ra * 64 + ca * 8);
                int rb = wn + t * 16 + l15;
                int cb = ((kk >> 3) + l4) ^ (rb & 7);
                bf[t] = *(const v8s*)(lsB + rb * 64 + cb * 8);
            }
#pragma unroll
            for (int i = 0; i < 4; i++)
#pragma unroll
                for (int j = 0; j < 4; j++)
                    acc[i][j] = __builtin_amdgcn_mfma_f32_16x16x32_bf16(af[i], bf[j], acc[i][j], 0, 0, 0);
        }
        __syncthreads();
    }
}

// ---------------- fp8 GEMM core ----------------
// A: [M x K] e4m3 row-major (K in BYTES), B: [N x K] e4m3 row-major (B^T input).
// BK=128 bytes -> byte-identical staging geometry to the bf16 core (16 KB/tile,
// XOR-swizzled 16B chunks). 4 MFMA k-steps of 32 per staging iter (2x ratio vs bf16).
__device__ __forceinline__ void gemm_core_fp8(const char* __restrict__ A,
                                              const char* __restrict__ B,
                                              int K, int m0, int n0,
                                              char* smem, v4f (&acc)[4][4])
{
    char* lsA = smem;             // 128 rows * 128 B
    char* lsB = smem + 16384;
    const int tid  = threadIdx.x;
    const int wave = tid >> 6, lane = tid & 63;
    const int l15 = lane & 15, l4 = lane >> 4;
    const int wm = (wave >> 1) << 6, wn = (wave & 1) << 6;

#pragma unroll
    for (int i = 0; i < 4; i++)
#pragma unroll
        for (int j = 0; j < 4; j++) acc[i][j] = (v4f)(0.0f);

    const int srow = lane >> 3;
    const int g    = (lane & 7) ^ srow;   // logical 16B chunk (of 8 per 128B row)

    for (int k0 = 0; k0 < K; k0 += 128) {
#pragma unroll
        for (int i = 0; i < 4; i++) {
            int ci  = wave * 4 + i;          // 16 chunk-groups of 8 rows
            int row = ci * 8 + srow;
            const char* ga = A + (size_t)(m0 + row) * K + k0 + g * 16;
            const char* gb = B + (size_t)(n0 + row) * K + k0 + g * 16;
            __builtin_amdgcn_global_load_lds((gp_t)ga, (lp_t)(lsA + ci * 1024), 16, 0, 0);
            __builtin_amdgcn_global_load_lds((gp_t)gb, (lp_t)(lsB + ci * 1024), 16, 0, 0);
        }
        __syncthreads();
#pragma unroll
        for (int kk = 0; kk < 128; kk += 32) {
            long af[4], bq[4];
            const int cbase = (kk >> 4) + (l4 >> 1);   // logical 16B chunk of fragment
            const int half  = (l4 & 1) * 8;
#pragma unroll
            for (int t = 0; t < 4; t++) {
                int ra = wm + t * 16 + l15;
                int ca = cbase ^ (ra & 7);
                af[t] = *(const long*)(lsA + ra * 128 + ca * 16 + half);
                int rb = wn + t * 16 + l15;
                int cb = cbase ^ (rb & 7);
                bq[t] = *(const long*)(lsB + rb * 128 + cb * 16 + half);
            }
#pragma unroll
            for (int i = 0; i < 4; i++)
#pragma unroll
                for (int j = 0; j < 4; j++)
                    acc[i][j] = __builtin_amdgcn_mfma_f32_16x16x32_fp8_fp8(af[i], bq[j], acc[i][j], 0, 0, 0);
        }
        __syncthreads();
    }
}

// ---------------- small kernels ----------------

__global__ void cvt_x(const float* __restrict__ x, short* __restrict__ xb) {
    size_t i = ((size_t)blockIdx.x * 256 + threadIdx.x) * 8;
    float4 a = *(const float4*)(x + i);
    float4 b = *(const float4*)(x + i + 4);
    v8s o;
    o[0] = f2b(a.x); o[1] = f2b(a.y); o[2] = f2b(a.z); o[3] = f2b(a.w);
    o[4] = f2b(b.x); o[5] = f2b(b.y); o[6] = f2b(b.z); o[7] = f2b(b.w);
    *(v8s*)(xb + i) = o;
}

__global__ void cvt_w(const float* __restrict__ Wq, const float* __restrict__ Wk,
                      const float* __restrict__ Wg, short* __restrict__ wbt) {
    __shared__ float t[64][68];
    const float* W = blockIdx.z == 0 ? Wq : (blockIdx.z == 1 ? Wk : Wg);
    int k0 = blockIdx.x * 64, n0 = blockIdx.y * 64;
    int tr = threadIdx.x >> 4, tc = threadIdx.x & 15;
#pragma unroll
    for (int p = 0; p < 4; p++) {
        int r = p * 16 + tr;
        float4 v = *(const float4*)(W + (size_t)(k0 + r) * DD + n0 + tc * 4);
        t[r][tc * 4 + 0] = v.x; t[r][tc * 4 + 1] = v.y;
        t[r][tc * 4 + 2] = v.z; t[r][tc * 4 + 3] = v.w;
    }
    __syncthreads();
#pragma unroll
    for (int p = 0; p < 4; p++) {
        int rr = p * 16 + tr;
        short4 s;
        s.x = f2b(t[tc * 4 + 0][rr]); s.y = f2b(t[tc * 4 + 1][rr]);
        s.z = f2b(t[tc * 4 + 2][rr]); s.w = f2b(t[tc * 4 + 3][rr]);
        *(short4*)(wbt + (size_t)(blockIdx.z * DD + n0 + rr) * DD + k0 + tc * 4) = s;
    }
}

__global__ void gemv_m(const float* __restrict__ x, const float* __restrict__ wv,
                       const float* __restrict__ bp, float* __restrict__ mout) {
    int row = blockIdx.x * 4 + (threadIdx.x >> 6);
    int lane = threadIdx.x & 63;
    const float* xr = x + (size_t)row * DD;
    float s = 0.f;
    for (int c = lane * 4; c < DD; c += 256) {
        float4 a = *(const float4*)(xr + c);
        float4 b = *(const float4*)(wv + c);
        s = fmaf(a.x, b.x, s); s = fmaf(a.y, b.y, s);
        s = fmaf(a.z, b.z, s); s = fmaf(a.w, b.w, s);
    }
    for (int o = 32; o; o >>= 1) s += __shfl_down(s, o);
    if (lane == 0) mout[row] = s + bp[0];
}

__global__ void gate_k(const float* __restrict__ m, float* __restrict__ gate) {
    __shared__ float sred[4];
    __shared__ float sbc[2];
    int tid = threadIdx.x, lane = tid & 63, wave = tid >> 6;
    float mx = -3.4e38f;
    for (int i = tid; i < NT; i += 256) mx = fmaxf(mx, m[i]);
    for (int o = 32; o; o >>= 1) mx = fmaxf(mx, __shfl_xor(mx, o));
    if (lane == 0) sred[wave] = mx;
    __syncthreads();
    if (tid == 0) sbc[0] = fmaxf(fmaxf(sred[0], sred[1]), fmaxf(sred[2], sred[3]));
    __syncthreads();
    float gmax = sbc[0];
    float s = 0.f;
    for (int i = tid; i < NT; i += 256) s += expf(m[i] - gmax);
    for (int o = 32; o; o >>= 1) s += __shfl_xor(s, o);
    if (lane == 0) sred[wave] = s;
    __syncthreads();
    if (tid == 0) sbc[1] = sred[0] + sred[1] + sred[2] + sred[3];
    __syncthreads();
    float inv = 1.f / sbc[1];
    for (int i = tid; i < NT; i += 256) gate[i] = expf(m[i] - gmax) * inv;
}

// q/k: subtract column mean (fp32), quantize to e4m3
__global__ void center_qk(const short* __restrict__ qh, const short* __restrict__ kh,
                          char* __restrict__ q8, char* __restrict__ k8,
                          const float* __restrict__ qs, const float* __restrict__ ks) {
    size_t idx = ((size_t)blockIdx.x * 256 + threadIdx.x) * 8;
    int col = (int)(idx & (DD - 1));
    v8s vq = *(const v8s*)(qh + idx);
    v8s vk = *(const v8s*)(kh + idx);
    const float scale = 1.f / (float)NT;
    float fq[8], fk[8];
#pragma unroll
    for (int j = 0; j < 8; j++) {
        fq[j] = b2f(vq[j]) - qs[col + j] * scale;
        fk[j] = b2f(vk[j]) - ks[col + j] * scale;
    }
    unsigned wq0 = __builtin_amdgcn_cvt_pk_fp8_f32(fq[0], fq[1], 0, false);
    wq0 = __builtin_amdgcn_cvt_pk_fp8_f32(fq[2], fq[3], wq0, true);
    unsigned wq1 = __builtin_amdgcn_cvt_pk_fp8_f32(fq[4], fq[5], 0, false);
    wq1 = __builtin_amdgcn_cvt_pk_fp8_f32(fq[6], fq[7], wq1, true);
    unsigned wk0 = __builtin_amdgcn_cvt_pk_fp8_f32(fk[0], fk[1], 0, false);
    wk0 = __builtin_amdgcn_cvt_pk_fp8_f32(fk[2], fk[3], wk0, true);
    unsigned wk1 = __builtin_amdgcn_cvt_pk_fp8_f32(fk[4], fk[5], 0, false);
    wk1 = __builtin_amdgcn_cvt_pk_fp8_f32(fk[6], fk[7], wk1, true);
    int2 oq; oq.x = (int)wq0; oq.y = (int)wq1;
    int2 ok; ok.x = (int)wk0; ok.y = (int)wk1;
    *(int2*)(q8 + idx) = oq;
    *(int2*)(k8 + idx) = ok;
}

// ---------------- GEMM kernels ----------------

// K1: C = x @ [Wq|Wk|Wg]  (M=8192, N=3072, K=1024), bf16 MFMA
__global__ __launch_bounds__(256, 2) void k_proj(
        const short* __restrict__ xb, const short* __restrict__ wbt,
        short* __restrict__ qh, short* __restrict__ kh, char* __restrict__ gbt,
        float* __restrict__ qsum, float* __restrict__ ksum, float* __restrict__ gsum) {
    __shared__ __align__(16) short smem[16384];   // 32 KB: staging / fp8 transpose bounce
    int bm, bn; tile_coords(blockIdx.x, 24, bm, bn);
    int m0 = bm * 128, n0 = bn * 128;
    v4f acc[4][4];
    gemm_core(xb, wbt, DD, m0, n0, smem, acc);

    const int tid = threadIdx.x, wave = tid >> 6, lane = tid & 63;
    const int l15 = lane & 15, l4 = lane >> 4;
    const int wm = (wave >> 1) << 6, wn = (wave & 1) << 6;
    int sec = n0 >> 10;            // 0=q 1=k 2=g
    int nloc = n0 & (DD - 1);

    if (sec < 2) {
        short* dst  = sec ? kh : qh;
        float* sums = sec ? ksum : qsum;
        float cs[4] = {0.f, 0.f, 0.f, 0.f};
#pragma unroll
        for (int i = 0; i < 4; i++)
#pragma unroll
            for (int j = 0; j < 4; j++)
#pragma unroll
                for (int v = 0; v < 4; v++) {
                    int row = m0 + wm + i * 16 + l4 * 4 + v;
                    int col = nloc + wn + j * 16 + l15;
                    dst[(size_t)row * DD + col] = f2b(acc[i][j][v]);
                    cs[j] += acc[i][j][v];
                }
#pragma unroll
        for (int j = 0; j < 4; j++)
            atomicAdd(&sums[nloc + wn + j * 16 + l15], cs[j]);
    } else {
        // g tile -> transposed fp8 store gbt[d][i] via LDS bounce (stride 144 B, 16-aligned)
        char* sc = (char*)smem;
        float cs[4] = {0.f, 0.f, 0.f, 0.f};
#pragma unroll
        for (int i = 0; i < 4; i++)
#pragma unroll
            for (int j = 0; j < 4; j++)
#pragma unroll
                for (int v = 0; v < 4; v++) {
                    int lr = wn + j * 16 + l15;            // local d
                    int lc = wm + i * 16 + l4 * 4 + v;     // local token
                    sc[lr * 144 + lc] = f2e4m3(acc[i][j][v]);
                    cs[j] += acc[i][j][v];
                }
        __syncthreads();
#pragma unroll
        for (int it = 0; it < 4; it++) {
            int c = it * 256 + tid;          // 1024 chunks of 16 bytes
            int dr = c >> 3, cm = (c & 7) * 16;
            int4 vv = *(const int4*)(sc + dr * 144 + cm);
            *(int4*)(gbt + (size_t)(nloc + dr) * NT + m0 + cm) = vv;
        }
#pragma unroll
        for (int j = 0; j < 4; j++)
            atomicAdd(&gsum[nloc + wn + j * 16 + l15], cs[j]);
    }
}

// K3: E = exp(c * q@k^T) e4m3, l += rowsum(E)   (M=N=8192, K=1024 bytes)
__global__ __launch_bounds__(256, 2) void k_score(
        const char* __restrict__ q8, const char* __restrict__ k8,
        char* __restrict__ E, float* __restrict__ l, const float* __restrict__ cptr) {
    __shared__ __align__(16) char smem[32768];
    int bm, bn; tile_coords(blockIdx.x, 64, bm, bn);
    int m0 = bm * 128, n0 = bn * 128;
    v4f acc[4][4];
    gemm_core_fp8(q8, k8, DD, m0, n0, smem, acc);

    const float cv = cptr[0];
    const int tid = threadIdx.x, wave = tid >> 6, lane = tid & 63;
    const int l15 = lane & 15, l4 = lane >> 4;
    const int wm = (wave >> 1) << 6, wn = (wave & 1) << 6;
#pragma unroll
    for (int i = 0; i < 4; i++)
#pragma unroll
        for (int v = 0; v < 4; v++) {
            int row = m0 + wm + i * 16 + l4 * 4 + v;
            float rsum = 0.f;
#pragma unroll
            for (int j = 0; j < 4; j++) {
                float e = __expf(cv * acc[i][j][v]);
                E[(size_t)row * NT + (n0 + wn + j * 16 + l15)] = f2e4m3(e);
                rsum += e;
            }
#pragma unroll
            for (int o = 1; o < 16; o <<= 1) rsum += __shfl_xor(rsum, o);
            if (l15 == 0) atomicAdd(&l[row], rsum);
        }
}

// K4: out = (E @ g)/l + gate*gsum + x   (M=8192, N=1024, K=8192 bytes)
__global__ __launch_bounds__(256, 2) void k_out(
        const char* __restrict__ E, const char* __restrict__ gbt,
        const float* __restrict__ l, const float* __restrict__ gate,
        const float* __restrict__ gsum, const float* __restrict__ x,
        float* __restrict__ out) {
    __shared__ __align__(16) char smem[32768];
    int bm, bn; tile_coords(blockIdx.x, 8, bm, bn);
    int m0 = bm * 128, n0 = bn * 128;
    v4f acc[4][4];
    gemm_core_fp8(E, gbt, NT, m0, n0, smem, acc);

    const int tid = threadIdx.x, wave = tid >> 6, lane = tid & 63;
    const int l15 = lane & 15, l4 = lane >> 4;
    const int wm = (wave >> 1) << 6, wn = (wave & 1) << 6;
#pragma unroll
    for (int i = 0; i < 4; i++)
#pragma unroll
        for (int v = 0; v < 4; v++) {
            int row = m0 + wm + i * 16 + l4 * 4 + v;
            float inv = 1.f / l[row];
            float gv  = gate[row];
#pragma unroll
            for (int j = 0; j < 4; j++) {
                int col = n0 + wn + j * 16 + l15;
                out[(size_t)row * DD + col] =
                    acc[i][j][v] * inv + gv * gsum[col] + x[(size_t)row * DD + col];
            }
        }
}

// ---------------- launch ----------------

extern "C" void kernel_launch(void* const* d_in, const int* in_sizes, int n_in,
                              void* d_out, int out_size, void* d_ws, size_t ws_size,
                              hipStream_t stream) {
    const float* x  = (const float*)d_in[0];
    const float* Wq = (const float*)d_in[1];
    const float* Wk = (const float*)d_in[2];
    const float* Wg = (const float*)d_in[3];
    const float* Wm = (const float*)d_in[4];
    const float* Wb = (const float*)d_in[5];
    const float* cp = (const float*)d_in[6];
    float* out = (float*)d_out;

    char* w = (char*)d_ws;
    size_t off = 0;
    auto alloc = [&](size_t bytes) -> void* {
        void* p = w + off;
        off += (bytes + 255) & ~(size_t)255;
        return p;
    };
    short* qh    = (short*)alloc((size_t)NT * DD * 2);      // 16 MB bf16 q_hat
    short* kh    = (short*)alloc((size_t)NT * DD * 2);      // 16 MB bf16 k_hat
    char*  q8    = (char*)alloc((size_t)NT * DD);           // 8 MB fp8 centered q
    char*  k8    = (char*)alloc((size_t)NT * DD);           // 8 MB fp8 centered k
    char*  gbt   = (char*)alloc((size_t)DD * NT);           // 8 MB fp8 g^T
    short* wbt   = (short*)alloc((size_t)3 * DD * DD * 2);  // 6 MB
    short* xb    = (short*)alloc((size_t)NT * DD * 2);      // 16 MB
    char*  E     = (char*)alloc((size_t)NT * NT);           // 64 MB fp8
    float* stats = (float*)alloc((3 * DD + 3 * NT) * 4);
    float* qsum = stats;
    float* ksum = stats + DD;
    float* gsum = stats + 2 * DD;
    float* lrow = stats + 3 * DD;
    float* mvec = lrow + NT;
    float* gate = mvec + NT;
    if (off > ws_size) return;

    hipMemsetAsync(stats, 0, (size_t)(3 * DD + NT) * 4, stream);

    cvt_x<<<NT * DD / (256 * 8), 256, 0, stream>>>(x, xb);
    cvt_w<<<dim3(16, 16, 3), 256, 0, stream>>>(Wq, Wk, Wg, wbt);
    gemv_m<<<NT / 4, 256, 0, stream>>>(x, Wm, Wb, mvec);
    gate_k<<<1, 256, 0, stream>>>(mvec, gate);
    k_proj<<<64 * 24, 256, 0, stream>>>(xb, wbt, qh, kh, gbt, qsum, ksum, gsum);
    center_qk<<<NT * DD / (256 * 8), 256, 0, stream>>>(qh, kh, q8, k8, qsum, ksum);
    k_score<<<64 * 64, 256, 0, stream>>>(q8, k8, E, lrow, cp);
    k_out<<<64 * 8, 256, 0, stream>>>(E, gbt, lrow, gate, gsum, x, out);
}

// Round 3
// 410.457 us; speedup vs baseline: 1.3107x; 1.1432x over previous
//
#include <hip/hip_runtime.h>
#include <math.h>

// N=8192 tokens, D=1024. All inputs fp32.
// out = (E@g)/l + gate*colsum(g) + x
// E = exp(c*q_hat@k_hat^T - beta_j), beta_j = c*mean(q_hat)·k_hat_j  (row-uniform
// centering terms cancel in E/rowsum(E) -> no k-centering, no q-centering pass)
// R3: k_score/k_out use MX-scaled fp8 MFMA (16x16x128, unit scales).

#define NT 8192
#define DD 1024

typedef float v4f __attribute__((ext_vector_type(4)));
typedef short v8s __attribute__((ext_vector_type(8)));
typedef int   v4i __attribute__((ext_vector_type(4)));
typedef int   v8i __attribute__((ext_vector_type(8)));

typedef const __attribute__((address_space(1))) void* gp_t;
typedef __attribute__((address_space(3))) void* lp_t;

__device__ __forceinline__ short f2b(float f) {
    unsigned u = __float_as_uint(f);
    return (short)((u + 0x7fffu + ((u >> 16) & 1u)) >> 16);   // RNE
}
__device__ __forceinline__ float b2f(short s) {
    return __uint_as_float(((unsigned)(unsigned short)s) << 16);
}
__device__ __forceinline__ char f2e4m3(float f) {
    unsigned p = __builtin_amdgcn_cvt_pk_fp8_f32(f, f, 0, false);
    return (char)(p & 0xff);
}

// supertile swizzle: bands of 16 row-tiles so concurrent blocks share A/B panels in L2/LLC
__device__ __forceinline__ void tile_coords(int bid, int tn, int& bm, int& bn) {
    const int SUP = 16;
    int per = SUP * tn;
    int band = bid / per, r = bid % per;
    bm = band * SUP + (r % SUP);
    bn = r / SUP;
}

// ---------------- bf16 GEMM core (k_proj) ----------------
__device__ __forceinline__ void gemm_core(const short* __restrict__ A,
                                          const short* __restrict__ B,
                                          int K, int m0, int n0,
                                          short* smem, v4f (&acc)[4][4])
{
    short* lsA = smem;            // 128*64 shorts
    short* lsB = smem + 8192;
    const int tid  = threadIdx.x;
    const int wave = tid >> 6, lane = tid & 63;
    const int l15 = lane & 15, l4 = lane >> 4;
    const int wm = (wave >> 1) << 6, wn = (wave & 1) << 6;

#pragma unroll
    for (int i = 0; i < 4; i++)
#pragma unroll
        for (int j = 0; j < 4; j++) acc[i][j] = (v4f)(0.0f);

    const int srow = lane >> 3;
    const int g    = (lane & 7) ^ srow;

    for (int k0 = 0; k0 < K; k0 += 64) {
#pragma unroll
        for (int i = 0; i < 4; i++) {
            int ci  = wave * 4 + i;
            int row = ci * 8 + srow;
            const short* ga = A + (size_t)(m0 + row) * K + k0 + g * 8;
            const short* gb = B + (size_t)(n0 + row) * K + k0 + g * 8;
            __builtin_amdgcn_global_load_lds((gp_t)ga, (lp_t)(lsA + ci * 512), 16, 0, 0);
            __builtin_amdgcn_global_load_lds((gp_t)gb, (lp_t)(lsB + ci * 512), 16, 0, 0);
        }
        __syncthreads();
#pragma unroll
        for (int kk = 0; kk < 64; kk += 32) {
            v8s af[4], bf[4];
#pragma unroll
            for (int t = 0; t < 4; t++) {
                int ra = wm + t * 16 + l15;
                int ca = ((kk >> 3) + l4) ^ (ra & 7);
                af[t] = *(const v8s*)(lsA + ra * 64 + ca * 8);
                int rb = wn + t * 16 + l15;
                int cb = ((kk >> 3) + l4) ^ (rb & 7);
                bf[t] = *(const v8s*)(lsB + rb * 64 + cb * 8);
            }
#pragma unroll
            for (int i = 0; i < 4; i++)
#pragma unroll
                for (int j = 0; j < 4; j++)
                    acc[i][j] = __builtin_amdgcn_mfma_f32_16x16x32_bf16(af[i], bf[j], acc[i][j], 0, 0, 0);
        }
        __syncthreads();
    }
}

// ---------------- MX fp8 GEMM core ----------------
// A: [M x K] e4m3 row-major (K in BYTES), B: [N x K] e4m3 row-major.
// BK=128 bytes; one 16x16x128 scaled MFMA per staging iter per (i,j).
// Fragment: lane holds 32 contiguous k-bytes (row=lane&15, kbase=(lane>>4)*32),
// fetched as 2x ds_read_b128 through the XOR-swizzled layout (conflict-free).
__device__ __forceinline__ void gemm_core_mx(const char* __restrict__ A,
                                             const char* __restrict__ B,
                                             int K, int m0, int n0,
                                             char* smem, v4f (&acc)[4][4])
{
    char* lsA = smem;             // 128 rows * 128 B
    char* lsB = smem + 16384;
    const int tid  = threadIdx.x;
    const int wave = tid >> 6, lane = tid & 63;
    const int l15 = lane & 15, l4 = lane >> 4;
    const int wm = (wave >> 1) << 6, wn = (wave & 1) << 6;

#pragma unroll
    for (int i = 0; i < 4; i++)
#pragma unroll
        for (int j = 0; j < 4; j++) acc[i][j] = (v4f)(0.0f);

    const int srow = lane >> 3;
    const int g    = (lane & 7) ^ srow;   // logical 16B chunk (of 8 per 128B row)

    for (int k0 = 0; k0 < K; k0 += 128) {
#pragma unroll
        for (int i = 0; i < 4; i++) {
            int ci  = wave * 4 + i;          // 16 chunk-groups of 8 rows
            int row = ci * 8 + srow;
            const char* ga = A + (size_t)(m0 + row) * K + k0 + g * 16;
            const char* gb = B + (size_t)(n0 + row) * K + k0 + g * 16;
            __builtin_amdgcn_global_load_lds((gp_t)ga, (lp_t)(lsA + ci * 1024), 16, 0, 0);
            __builtin_amdgcn_global_load_lds((gp_t)gb, (lp_t)(lsB + ci * 1024), 16, 0, 0);
        }
        __syncthreads();
        v8i af[4], bq[4];
#pragma unroll
        for (int t = 0; t < 4; t++) {
            int ra = wm + t * 16 + l15;
            int a0 = (2 * l4) ^ (ra & 7), a1 = (2 * l4 + 1) ^ (ra & 7);
            v4i lo = *(const v4i*)(lsA + ra * 128 + a0 * 16);
            v4i hi = *(const v4i*)(lsA + ra * 128 + a1 * 16);
            af[t][0] = lo[0]; af[t][1] = lo[1]; af[t][2] = lo[2]; af[t][3] = lo[3];
            af[t][4] = hi[0]; af[t][5] = hi[1]; af[t][6] = hi[2]; af[t][7] = hi[3];
            int rb = wn + t * 16 + l15;
            int b0 = (2 * l4) ^ (rb & 7), b1 = (2 * l4 + 1) ^ (rb & 7);
            v4i blo = *(const v4i*)(lsB + rb * 128 + b0 * 16);
            v4i bhi = *(const v4i*)(lsB + rb * 128 + b1 * 16);
            bq[t][0] = blo[0]; bq[t][1] = blo[1]; bq[t][2] = blo[2]; bq[t][3] = blo[3];
            bq[t][4] = bhi[0]; bq[t][5] = bhi[1]; bq[t][6] = bhi[2]; bq[t][7] = bhi[3];
        }
#pragma unroll
        for (int i = 0; i < 4; i++)
#pragma unroll
            for (int j = 0; j < 4; j++)
                acc[i][j] = __builtin_amdgcn_mfma_scale_f32_16x16x128_f8f6f4(
                    af[i], bq[j], acc[i][j], 0, 0,
                    0, 0x7f7f7f7f, 0, 0x7f7f7f7f);   // e8m0 0x7f = 1.0 scales
        __syncthreads();
    }
}

// ---------------- small kernels ----------------

__global__ void cvt_x(const float* __restrict__ x, short* __restrict__ xb) {
    size_t i = ((size_t)blockIdx.x * 256 + threadIdx.x) * 8;
    float4 a = *(const float4*)(x + i);
    float4 b = *(const float4*)(x + i + 4);
    v8s o;
    o[0] = f2b(a.x); o[1] = f2b(a.y); o[2] = f2b(a.z); o[3] = f2b(a.w);
    o[4] = f2b(b.x); o[5] = f2b(b.y); o[6] = f2b(b.z); o[7] = f2b(b.w);
    *(v8s*)(xb + i) = o;
}

__global__ void cvt_w(const float* __restrict__ Wq, const float* __restrict__ Wk,
                      const float* __restrict__ Wg, short* __restrict__ wbt) {
    __shared__ float t[64][68];
    const float* W = blockIdx.z == 0 ? Wq : (blockIdx.z == 1 ? Wk : Wg);
    int k0 = blockIdx.x * 64, n0 = blockIdx.y * 64;
    int tr = threadIdx.x >> 4, tc = threadIdx.x & 15;
#pragma unroll
    for (int p = 0; p < 4; p++) {
        int r = p * 16 + tr;
        float4 v = *(const float4*)(W + (size_t)(k0 + r) * DD + n0 + tc * 4);
        t[r][tc * 4 + 0] = v.x; t[r][tc * 4 + 1] = v.y;
        t[r][tc * 4 + 2] = v.z; t[r][tc * 4 + 3] = v.w;
    }
    __syncthreads();
#pragma unroll
    for (int p = 0; p < 4; p++) {
        int rr = p * 16 + tr;
        short4 s;
        s.x = f2b(t[tc * 4 + 0][rr]); s.y = f2b(t[tc * 4 + 1][rr]);
        s.z = f2b(t[tc * 4 + 2][rr]); s.w = f2b(t[tc * 4 + 3][rr]);
        *(short4*)(wbt + (size_t)(blockIdx.z * DD + n0 + rr) * DD + k0 + tc * 4) = s;
    }
}

__global__ void gemv_m(const float* __restrict__ x, const float* __restrict__ wv,
                       const float* __restrict__ bp, float* __restrict__ mout) {
    int row = blockIdx.x * 4 + (threadIdx.x >> 6);
    int lane = threadIdx.x & 63;
    const float* xr = x + (size_t)row * DD;
    float s = 0.f;
    for (int c = lane * 4; c < DD; c += 256) {
        float4 a = *(const float4*)(xr + c);
        float4 b = *(const float4*)(wv + c);
        s = fmaf(a.x, b.x, s); s = fmaf(a.y, b.y, s);
        s = fmaf(a.z, b.z, s); s = fmaf(a.w, b.w, s);
    }
    for (int o = 32; o; o >>= 1) s += __shfl_down(s, o);
    if (lane == 0) mout[row] = s + bp[0];
}

__global__ void gate_k(const float* __restrict__ m, float* __restrict__ gate) {
    __shared__ float sred[4];
    __shared__ float sbc[2];
    int tid = threadIdx.x, lane = tid & 63, wave = tid >> 6;
    float mx = -3.4e38f;
    for (int i = tid; i < NT; i += 256) mx = fmaxf(mx, m[i]);
    for (int o = 32; o; o >>= 1) mx = fmaxf(mx, __shfl_xor(mx, o));
    if (lane == 0) sred[wave] = mx;
    __syncthreads();
    if (tid == 0) sbc[0] = fmaxf(fmaxf(sred[0], sred[1]), fmaxf(sred[2], sred[3]));
    __syncthreads();
    float gmax = sbc[0];
    float s = 0.f;
    for (int i = tid; i < NT; i += 256) s += expf(m[i] - gmax);
    for (int o = 32; o; o >>= 1) s += __shfl_xor(s, o);
    if (lane == 0) sred[wave] = s;
    __syncthreads();
    if (tid == 0) sbc[1] = sred[0] + sred[1] + sred[2] + sred[3];
    __syncthreads();
    float inv = 1.f / sbc[1];
    for (int i = tid; i < NT; i += 256) gate[i] = expf(m[i] - gmax) * inv;
}

// beta[j] = (c/NT) * sum_d qsum[d] * k8[j][d]   (one wave per row)
__global__ void beta_gemv(const char* __restrict__ k8, const float* __restrict__ qsum,
                          const float* __restrict__ cp, float* __restrict__ beta) {
    int row = blockIdx.x * 4 + (threadIdx.x >> 6);
    int lane = threadIdx.x & 63;
    v4i kv = *(const v4i*)(k8 + (size_t)row * DD + lane * 16);
    const float* qs = qsum + lane * 16;
    float s = 0.f;
#pragma unroll
    for (int w = 0; w < 4; w++) {
        float4 qv = *(const float4*)(qs + w * 4);
        int word = kv[w];
        s = fmaf(__builtin_amdgcn_cvt_f32_fp8(word, 0), qv.x, s);
        s = fmaf(__builtin_amdgcn_cvt_f32_fp8(word, 1), qv.y, s);
        s = fmaf(__builtin_amdgcn_cvt_f32_fp8(word, 2), qv.z, s);
        s = fmaf(__builtin_amdgcn_cvt_f32_fp8(word, 3), qv.w, s);
    }
    for (int o = 32; o; o >>= 1) s += __shfl_down(s, o);
    if (lane == 0) beta[row] = s * cp[0] / (float)NT;
}

// ---------------- GEMM kernels ----------------

// K1: C = x @ [Wq|Wk|Wg]  (M=8192, N=3072, K=1024), bf16 MFMA, fp8 outputs
__global__ __launch_bounds__(256, 2) void k_proj(
        const short* __restrict__ xb, const short* __restrict__ wbt,
        char* __restrict__ q8, char* __restrict__ k8, char* __restrict__ gbt,
        float* __restrict__ qsum, float* __restrict__ gsum) {
    __shared__ __align__(16) short smem[16384];
    int bm, bn; tile_coords(blockIdx.x, 24, bm, bn);
    int m0 = bm * 128, n0 = bn * 128;
    v4f acc[4][4];
    gemm_core(xb, wbt, DD, m0, n0, smem, acc);

    const int tid = threadIdx.x, wave = tid >> 6, lane = tid & 63;
    const int l15 = lane & 15, l4 = lane >> 4;
    const int wm = (wave >> 1) << 6, wn = (wave & 1) << 6;
    int sec = n0 >> 10;            // 0=q 1=k 2=g
    int nloc = n0 & (DD - 1);

    if (sec < 2) {
        char* dst = sec ? k8 : q8;
        float cs[4] = {0.f, 0.f, 0.f, 0.f};
#pragma unroll
        for (int i = 0; i < 4; i++)
#pragma unroll
            for (int j = 0; j < 4; j++)
#pragma unroll
                for (int v = 0; v < 4; v++) {
                    int row = m0 + wm + i * 16 + l4 * 4 + v;
                    int col = nloc + wn + j * 16 + l15;
                    dst[(size_t)row * DD + col] = f2e4m3(acc[i][j][v]);
                    cs[j] += acc[i][j][v];
                }
        if (sec == 0)
#pragma unroll
            for (int j = 0; j < 4; j++)
                atomicAdd(&qsum[nloc + wn + j * 16 + l15], cs[j]);
    } else {
        // g tile -> transposed fp8 store gbt[d][i] via LDS bounce
        char* sc = (char*)smem;
        float cs[4] = {0.f, 0.f, 0.f, 0.f};
#pragma unroll
        for (int i = 0; i < 4; i++)
#pragma unroll
            for (int j = 0; j < 4; j++)
#pragma unroll
                for (int v = 0; v < 4; v++) {
                    int lr = wn + j * 16 + l15;            // local d
                    int lc = wm + i * 16 + l4 * 4 + v;     // local token
                    sc[lr * 144 + lc] = f2e4m3(acc[i][j][v]);
                    cs[j] += acc[i][j][v];
                }
        __syncthreads();
#pragma unroll
        for (int it = 0; it < 4; it++) {
            int c = it * 256 + tid;
            int dr = c >> 3, cm = (c & 7) * 16;
            int4 vv = *(const int4*)(sc + dr * 144 + cm);
            *(int4*)(gbt + (size_t)(nloc + dr) * NT + m0 + cm) = vv;
        }
#pragma unroll
        for (int j = 0; j < 4; j++)
            atomicAdd(&gsum[nloc + wn + j * 16 + l15], cs[j]);
    }
}

// K3: E = exp(c*q@k^T - beta_j) e4m3, l += rowsum(E)
__global__ __launch_bounds__(256, 2) void k_score(
        const char* __restrict__ q8, const char* __restrict__ k8,
        char* __restrict__ E, float* __restrict__ l, const float* __restrict__ cptr,
        const float* __restrict__ beta) {
    __shared__ __align__(16) char smem[32768];
    int bm, bn; tile_coords(blockIdx.x, 64, bm, bn);
    int m0 = bm * 128, n0 = bn * 128;
    v4f acc[4][4];
    gemm_core_mx(q8, k8, DD, m0, n0, smem, acc);

    const float cv = cptr[0];
    const int tid = threadIdx.x, wave = tid >> 6, lane = tid & 63;
    const int l15 = lane & 15, l4 = lane >> 4;
    const int wm = (wave >> 1) << 6, wn = (wave & 1) << 6;
    float bj[4];
#pragma unroll
    for (int j = 0; j < 4; j++) bj[j] = beta[n0 + wn + j * 16 + l15];
#pragma unroll
    for (int i = 0; i < 4; i++)
#pragma unroll
        for (int v = 0; v < 4; v++) {
            int row = m0 + wm + i * 16 + l4 * 4 + v;
            float rsum = 0.f;
#pragma unroll
            for (int j = 0; j < 4; j++) {
                float e = __expf(cv * acc[i][j][v] - bj[j]);
                E[(size_t)row * NT + (n0 + wn + j * 16 + l15)] = f2e4m3(e);
                rsum += e;
            }
#pragma unroll
            for (int o = 1; o < 16; o <<= 1) rsum += __shfl_xor(rsum, o);
            if (l15 == 0) atomicAdd(&l[row], rsum);
        }
}

// K4: out = (E @ g)/l + gate*gsum + x
__global__ __launch_bounds__(256, 2) void k_out(
        const char* __restrict__ E, const char* __restrict__ gbt,
        const float* __restrict__ l, const float* __restrict__ gate,
        const float* __restrict__ gsum, const float* __restrict__ x,
        float* __restrict__ out) {
    __shared__ __align__(16) char smem[32768];
    int bm, bn; tile_coords(blockIdx.x, 8, bm, bn);
    int m0 = bm * 128, n0 = bn * 128;
    v4f acc[4][4];
    gemm_core_mx(E, gbt, NT, m0, n0, smem, acc);

    const int tid = threadIdx.x, wave = tid >> 6, lane = tid & 63;
    const int l15 = lane & 15, l4 = lane >> 4;
    const int wm = (wave >> 1) << 6, wn = (wave & 1) << 6;
#pragma unroll
    for (int i = 0; i < 4; i++)
#pragma unroll
        for (int v = 0; v < 4; v++) {
            int row = m0 + wm + i * 16 + l4 * 4 + v;
            float inv = 1.f / l[row];
            float gv  = gate[row];
#pragma unroll
            for (int j = 0; j < 4; j++) {
                int col = n0 + wn + j * 16 + l15;
                out[(size_t)row * DD + col] =
                    acc[i][j][v] * inv + gv * gsum[col] + x[(size_t)row * DD + col];
            }
        }
}

// ---------------- launch ----------------

extern "C" void kernel_launch(void* const* d_in, const int* in_sizes, int n_in,
                              void* d_out, int out_size, void* d_ws, size_t ws_size,
                              hipStream_t stream) {
    const float* x  = (const float*)d_in[0];
    const float* Wq = (const float*)d_in[1];
    const float* Wk = (const float*)d_in[2];
    const float* Wg = (const float*)d_in[3];
    const float* Wm = (const float*)d_in[4];
    const float* Wb = (const float*)d_in[5];
    const float* cp = (const float*)d_in[6];
    float* out = (float*)d_out;

    char* w = (char*)d_ws;
    size_t off = 0;
    auto alloc = [&](size_t bytes) -> void* {
        void* p = w + off;
        off += (bytes + 255) & ~(size_t)255;
        return p;
    };
    char*  q8    = (char*)alloc((size_t)NT * DD);           // 8 MB fp8 q_hat
    char*  k8    = (char*)alloc((size_t)NT * DD);           // 8 MB fp8 k_hat
    char*  gbt   = (char*)alloc((size_t)DD * NT);           // 8 MB fp8 g^T
    short* wbt   = (short*)alloc((size_t)3 * DD * DD * 2);  // 6 MB
    short* xb    = (short*)alloc((size_t)NT * DD * 2);      // 16 MB
    char*  E     = (char*)alloc((size_t)NT * NT);           // 64 MB fp8
    float* stats = (float*)alloc((2 * DD + 4 * NT) * 4);
    float* qsum = stats;
    float* gsum = stats + DD;
    float* lrow = stats + 2 * DD;          // zeroed region ends here
    float* mvec = lrow + NT;
    float* gate = mvec + NT;
    float* beta = gate + NT;
    if (off > ws_size) return;

    hipMemsetAsync(stats, 0, (size_t)(2 * DD + NT) * 4, stream);

    cvt_x<<<NT * DD / (256 * 8), 256, 0, stream>>>(x, xb);
    cvt_w<<<dim3(16, 16, 3), 256, 0, stream>>>(Wq, Wk, Wg, wbt);
    gemv_m<<<NT / 4, 256, 0, stream>>>(x, Wm, Wb, mvec);
    gate_k<<<1, 256, 0, stream>>>(mvec, gate);
    k_proj<<<64 * 24, 256, 0, stream>>>(xb, wbt, q8, k8, gbt, qsum, gsum);
    beta_gemv<<<NT / 4, 256, 0, stream>>>(k8, qsum, cp, beta);
    k_score<<<64 * 64, 256, 0, stream>>>(q8, k8, E, lrow, cp, beta);
    k_out<<<64 * 8, 256, 0, stream>>>(E, gbt, lrow, gate, gsum, x, out);
}

// Round 4
// 406.601 us; speedup vs baseline: 1.3231x; 1.0095x over previous
//
#include <hip/hip_runtime.h>
#include <math.h>

// N=8192 tokens, D=1024. All inputs fp32.
// out = (E@g)/l + gate*colsum(g) + x
// E = exp(c*q_hat@k_hat^T - beta_j), beta_j = c*mean(q_hat)·k_hat_j  (row-uniform
// centering terms cancel in E/rowsum(E)); gate = exp(m)/sum(exp(m)), no max needed.
// R4: k_score back to non-scaled fp8 core (R2-measured 120us; MX regressed at K=1024),
//     k_out stays MX; gate fused into x_prep (one pass over x, no single-block kernel).

#define NT 8192
#define DD 1024

typedef float v4f __attribute__((ext_vector_type(4)));
typedef short v8s __attribute__((ext_vector_type(8)));
typedef int   v4i __attribute__((ext_vector_type(4)));
typedef int   v8i __attribute__((ext_vector_type(8)));

typedef const __attribute__((address_space(1))) void* gp_t;
typedef __attribute__((address_space(3))) void* lp_t;

__device__ __forceinline__ short f2b(float f) {
    unsigned u = __float_as_uint(f);
    return (short)((u + 0x7fffu + ((u >> 16) & 1u)) >> 16);   // RNE
}
__device__ __forceinline__ char f2e4m3(float f) {
    unsigned p = __builtin_amdgcn_cvt_pk_fp8_f32(f, f, 0, false);
    return (char)(p & 0xff);
}

// supertile swizzle: bands of 16 row-tiles so concurrent blocks share A/B panels in L2/LLC
__device__ __forceinline__ void tile_coords(int bid, int tn, int& bm, int& bn) {
    const int SUP = 16;
    int per = SUP * tn;
    int band = bid / per, r = bid % per;
    bm = band * SUP + (r % SUP);
    bn = r / SUP;
}

// ---------------- bf16 GEMM core (k_proj) ----------------
__device__ __forceinline__ void gemm_core(const short* __restrict__ A,
                                          const short* __restrict__ B,
                                          int K, int m0, int n0,
                                          short* smem, v4f (&acc)[4][4])
{
    short* lsA = smem;            // 128*64 shorts
    short* lsB = smem + 8192;
    const int tid  = threadIdx.x;
    const int wave = tid >> 6, lane = tid & 63;
    const int l15 = lane & 15, l4 = lane >> 4;
    const int wm = (wave >> 1) << 6, wn = (wave & 1) << 6;

#pragma unroll
    for (int i = 0; i < 4; i++)
#pragma unroll
        for (int j = 0; j < 4; j++) acc[i][j] = (v4f)(0.0f);

    const int srow = lane >> 3;
    const int g    = (lane & 7) ^ srow;

    for (int k0 = 0; k0 < K; k0 += 64) {
#pragma unroll
        for (int i = 0; i < 4; i++) {
            int ci  = wave * 4 + i;
            int row = ci * 8 + srow;
            const short* ga = A + (size_t)(m0 + row) * K + k0 + g * 8;
            const short* gb = B + (size_t)(n0 + row) * K + k0 + g * 8;
            __builtin_amdgcn_global_load_lds((gp_t)ga, (lp_t)(lsA + ci * 512), 16, 0, 0);
            __builtin_amdgcn_global_load_lds((gp_t)gb, (lp_t)(lsB + ci * 512), 16, 0, 0);
        }
        __syncthreads();
#pragma unroll
        for (int kk = 0; kk < 64; kk += 32) {
            v8s af[4], bf[4];
#pragma unroll
            for (int t = 0; t < 4; t++) {
                int ra = wm + t * 16 + l15;
                int ca = ((kk >> 3) + l4) ^ (ra & 7);
                af[t] = *(const v8s*)(lsA + ra * 64 + ca * 8);
                int rb = wn + t * 16 + l15;
                int cb = ((kk >> 3) + l4) ^ (rb & 7);
                bf[t] = *(const v8s*)(lsB + rb * 64 + cb * 8);
            }
#pragma unroll
            for (int i = 0; i < 4; i++)
#pragma unroll
                for (int j = 0; j < 4; j++)
                    acc[i][j] = __builtin_amdgcn_mfma_f32_16x16x32_bf16(af[i], bf[j], acc[i][j], 0, 0, 0);
        }
        __syncthreads();
    }
}

// ---------------- fp8 GEMM core (k_score; R2-measured 120us) ----------------
// A: [M x K] e4m3 row-major (K in BYTES), B: [N x K] e4m3 row-major.
// BK=128 bytes; 4 MFMA k-steps of 32 per staging iter.
__device__ __forceinline__ void gemm_core_fp8(const char* __restrict__ A,
                                              const char* __restrict__ B,
                                              int K, int m0, int n0,
                                              char* smem, v4f (&acc)[4][4])
{
    char* lsA = smem;             // 128 rows * 128 B
    char* lsB = smem + 16384;
    const int tid  = threadIdx.x;
    const int wave = tid >> 6, lane = tid & 63;
    const int l15 = lane & 15, l4 = lane >> 4;
    const int wm = (wave >> 1) << 6, wn = (wave & 1) << 6;

#pragma unroll
    for (int i = 0; i < 4; i++)
#pragma unroll
        for (int j = 0; j < 4; j++) acc[i][j] = (v4f)(0.0f);

    const int srow = lane >> 3;
    const int g    = (lane & 7) ^ srow;   // logical 16B chunk (of 8 per 128B row)

    for (int k0 = 0; k0 < K; k0 += 128) {
#pragma unroll
        for (int i = 0; i < 4; i++) {
            int ci  = wave * 4 + i;          // 16 chunk-groups of 8 rows
            int row = ci * 8 + srow;
            const char* ga = A + (size_t)(m0 + row) * K + k0 + g * 16;
            const char* gb = B + (size_t)(n0 + row) * K + k0 + g * 16;
            __builtin_amdgcn_global_load_lds((gp_t)ga, (lp_t)(lsA + ci * 1024), 16, 0, 0);
            __builtin_amdgcn_global_load_lds((gp_t)gb, (lp_t)(lsB + ci * 1024), 16, 0, 0);
        }
        __syncthreads();
#pragma unroll
        for (int kk = 0; kk < 128; kk += 32) {
            long af[4], bq[4];
            const int cbase = (kk >> 4) + (l4 >> 1);
            const int half  = (l4 & 1) * 8;
#pragma unroll
            for (int t = 0; t < 4; t++) {
                int ra = wm + t * 16 + l15;
                int ca = cbase ^ (ra & 7);
                af[t] = *(const long*)(lsA + ra * 128 + ca * 16 + half);
                int rb = wn + t * 16 + l15;
                int cb = cbase ^ (rb & 7);
                bq[t] = *(const long*)(lsB + rb * 128 + cb * 16 + half);
            }
#pragma unroll
            for (int i = 0; i < 4; i++)
#pragma unroll
                for (int j = 0; j < 4; j++)
                    acc[i][j] = __builtin_amdgcn_mfma_f32_16x16x32_fp8_fp8(af[i], bq[j], acc[i][j], 0, 0, 0);
        }
        __syncthreads();
    }
}

// ---------------- MX fp8 GEMM core (k_out; K=8192 amortizes) ----------------
__device__ __forceinline__ void gemm_core_mx(const char* __restrict__ A,
                                             const char* __restrict__ B,
                                             int K, int m0, int n0,
                                             char* smem, v4f (&acc)[4][4])
{
    char* lsA = smem;             // 128 rows * 128 B
    char* lsB = smem + 16384;
    const int tid  = threadIdx.x;
    const int wave = tid >> 6, lane = tid & 63;
    const int l15 = lane & 15, l4 = lane >> 4;
    const int wm = (wave >> 1) << 6, wn = (wave & 1) << 6;

#pragma unroll
    for (int i = 0; i < 4; i++)
#pragma unroll
        for (int j = 0; j < 4; j++) acc[i][j] = (v4f)(0.0f);

    const int srow = lane >> 3;
    const int g    = (lane & 7) ^ srow;

    for (int k0 = 0; k0 < K; k0 += 128) {
#pragma unroll
        for (int i = 0; i < 4; i++) {
            int ci  = wave * 4 + i;
            int row = ci * 8 + srow;
            const char* ga = A + (size_t)(m0 + row) * K + k0 + g * 16;
            const char* gb = B + (size_t)(n0 + row) * K + k0 + g * 16;
            __builtin_amdgcn_global_load_lds((gp_t)ga, (lp_t)(lsA + ci * 1024), 16, 0, 0);
            __builtin_amdgcn_global_load_lds((gp_t)gb, (lp_t)(lsB + ci * 1024), 16, 0, 0);
        }
        __syncthreads();
        v8i af[4], bq[4];
#pragma unroll
        for (int t = 0; t < 4; t++) {
            int ra = wm + t * 16 + l15;
            int a0 = (2 * l4) ^ (ra & 7), a1 = (2 * l4 + 1) ^ (ra & 7);
            v4i lo = *(const v4i*)(lsA + ra * 128 + a0 * 16);
            v4i hi = *(const v4i*)(lsA + ra * 128 + a1 * 16);
            af[t][0] = lo[0]; af[t][1] = lo[1]; af[t][2] = lo[2]; af[t][3] = lo[3];
            af[t][4] = hi[0]; af[t][5] = hi[1]; af[t][6] = hi[2]; af[t][7] = hi[3];
            int rb = wn + t * 16 + l15;
            int b0 = (2 * l4) ^ (rb & 7), b1 = (2 * l4 + 1) ^ (rb & 7);
            v4i blo = *(const v4i*)(lsB + rb * 128 + b0 * 16);
            v4i bhi = *(const v4i*)(lsB + rb * 128 + b1 * 16);
            bq[t][0] = blo[0]; bq[t][1] = blo[1]; bq[t][2] = blo[2]; bq[t][3] = blo[3];
            bq[t][4] = bhi[0]; bq[t][5] = bhi[1]; bq[t][6] = bhi[2]; bq[t][7] = bhi[3];
        }
#pragma unroll
        for (int i = 0; i < 4; i++)
#pragma unroll
            for (int j = 0; j < 4; j++)
                acc[i][j] = __builtin_amdgcn_mfma_scale_f32_16x16x128_f8f6f4(
                    af[i], bq[j], acc[i][j], 0, 0,
                    0, 0x7f7f7f7f, 0, 0x7f7f7f7f);   // e8m0 0x7f = 1.0
        __syncthreads();
    }
}

// ---------------- small kernels ----------------

// Fused: x -> bf16 xb; m = x.Wm + b; em = exp(m); gden += em (block-reduced atomic).
// One wave per row, 4 rows/block.
__global__ void x_prep(const float* __restrict__ x, const float* __restrict__ wv,
                       const float* __restrict__ bp, short* __restrict__ xb,
                       float* __restrict__ em, float* __restrict__ gden) {
    __shared__ float sred[4];
    int wv_id = threadIdx.x >> 6;
    int row = blockIdx.x * 4 + wv_id;
    int lane = threadIdx.x & 63;
    const float* xr = x + (size_t)row * DD;
    short* xbr = xb + (size_t)row * DD;
    float s = 0.f;
    for (int c = lane * 4; c < DD; c += 256) {
        float4 a = *(const float4*)(xr + c);
        float4 b = *(const float4*)(wv + c);
        s = fmaf(a.x, b.x, s); s = fmaf(a.y, b.y, s);
        s = fmaf(a.z, b.z, s); s = fmaf(a.w, b.w, s);
        short4 o;
        o.x = f2b(a.x); o.y = f2b(a.y); o.z = f2b(a.z); o.w = f2b(a.w);
        *(short4*)(xbr + c) = o;
    }
    for (int o = 32; o; o >>= 1) s += __shfl_down(s, o);
    if (lane == 0) {
        float e = __expf(s + bp[0]);
        em[row] = e;
        sred[wv_id] = e;
    }
    __syncthreads();
    if (threadIdx.x == 0)
        atomicAdd(gden, sred[0] + sred[1] + sred[2] + sred[3]);
}

__global__ void cvt_w(const float* __restrict__ Wq, const float* __restrict__ Wk,
                      const float* __restrict__ Wg, short* __restrict__ wbt) {
    __shared__ float t[64][68];
    const float* W = blockIdx.z == 0 ? Wq : (blockIdx.z == 1 ? Wk : Wg);
    int k0 = blockIdx.x * 64, n0 = blockIdx.y * 64;
    int tr = threadIdx.x >> 4, tc = threadIdx.x & 15;
#pragma unroll
    for (int p = 0; p < 4; p++) {
        int r = p * 16 + tr;
        float4 v = *(const float4*)(W + (size_t)(k0 + r) * DD + n0 + tc * 4);
        t[r][tc * 4 + 0] = v.x; t[r][tc * 4 + 1] = v.y;
        t[r][tc * 4 + 2] = v.z; t[r][tc * 4 + 3] = v.w;
    }
    __syncthreads();
#pragma unroll
    for (int p = 0; p < 4; p++) {
        int rr = p * 16 + tr;
        short4 s;
        s.x = f2b(t[tc * 4 + 0][rr]); s.y = f2b(t[tc * 4 + 1][rr]);
        s.z = f2b(t[tc * 4 + 2][rr]); s.w = f2b(t[tc * 4 + 3][rr]);
        *(short4*)(wbt + (size_t)(blockIdx.z * DD + n0 + rr) * DD + k0 + tc * 4) = s;
    }
}

// beta[j] = (c/NT) * sum_d qsum[d] * k8[j][d]   (one wave per row)
__global__ void beta_gemv(const char* __restrict__ k8, const float* __restrict__ qsum,
                          const float* __restrict__ cp, float* __restrict__ beta) {
    int row = blockIdx.x * 4 + (threadIdx.x >> 6);
    int lane = threadIdx.x & 63;
    v4i kv = *(const v4i*)(k8 + (size_t)row * DD + lane * 16);
    const float* qs = qsum + lane * 16;
    float s = 0.f;
#pragma unroll
    for (int w = 0; w < 4; w++) {
        float4 qv = *(const float4*)(qs + w * 4);
        int word = kv[w];
        s = fmaf(__builtin_amdgcn_cvt_f32_fp8(word, 0), qv.x, s);
        s = fmaf(__builtin_amdgcn_cvt_f32_fp8(word, 1), qv.y, s);
        s = fmaf(__builtin_amdgcn_cvt_f32_fp8(word, 2), qv.z, s);
        s = fmaf(__builtin_amdgcn_cvt_f32_fp8(word, 3), qv.w, s);
    }
    for (int o = 32; o; o >>= 1) s += __shfl_down(s, o);
    if (lane == 0) beta[row] = s * cp[0] / (float)NT;
}

// ---------------- GEMM kernels ----------------

// K1: C = x @ [Wq|Wk|Wg]  (M=8192, N=3072, K=1024), bf16 MFMA, fp8 outputs
__global__ __launch_bounds__(256, 2) void k_proj(
        const short* __restrict__ xb, const short* __restrict__ wbt,
        char* __restrict__ q8, char* __restrict__ k8, char* __restrict__ gbt,
        float* __restrict__ qsum, float* __restrict__ gsum) {
    __shared__ __align__(16) short smem[16384];
    int bm, bn; tile_coords(blockIdx.x, 24, bm, bn);
    int m0 = bm * 128, n0 = bn * 128;
    v4f acc[4][4];
    gemm_core(xb, wbt, DD, m0, n0, smem, acc);

    const int tid = threadIdx.x, wave = tid >> 6, lane = tid & 63;
    const int l15 = lane & 15, l4 = lane >> 4;
    const int wm = (wave >> 1) << 6, wn = (wave & 1) << 6;
    int sec = n0 >> 10;            // 0=q 1=k 2=g
    int nloc = n0 & (DD - 1);

    if (sec < 2) {
        char* dst = sec ? k8 : q8;
        float cs[4] = {0.f, 0.f, 0.f, 0.f};
#pragma unroll
        for (int i = 0; i < 4; i++)
#pragma unroll
            for (int j = 0; j < 4; j++)
#pragma unroll
                for (int v = 0; v < 4; v++) {
                    int row = m0 + wm + i * 16 + l4 * 4 + v;
                    int col = nloc + wn + j * 16 + l15;
                    dst[(size_t)row * DD + col] = f2e4m3(acc[i][j][v]);
                    cs[j] += acc[i][j][v];
                }
        if (sec == 0)
#pragma unroll
            for (int j = 0; j < 4; j++)
                atomicAdd(&qsum[nloc + wn + j * 16 + l15], cs[j]);
    } else {
        // g tile -> transposed fp8 store gbt[d][i] via LDS bounce
        char* sc = (char*)smem;
        float cs[4] = {0.f, 0.f, 0.f, 0.f};
#pragma unroll
        for (int i = 0; i < 4; i++)
#pragma unroll
            for (int j = 0; j < 4; j++)
#pragma unroll
                for (int v = 0; v < 4; v++) {
                    int lr = wn + j * 16 + l15;            // local d
                    int lc = wm + i * 16 + l4 * 4 + v;     // local token
                    sc[lr * 144 + lc] = f2e4m3(acc[i][j][v]);
                    cs[j] += acc[i][j][v];
                }
        __syncthreads();
#pragma unroll
        for (int it = 0; it < 4; it++) {
            int c = it * 256 + tid;
            int dr = c >> 3, cm = (c & 7) * 16;
            int4 vv = *(const int4*)(sc + dr * 144 + cm);
            *(int4*)(gbt + (size_t)(nloc + dr) * NT + m0 + cm) = vv;
        }
#pragma unroll
        for (int j = 0; j < 4; j++)
            atomicAdd(&gsum[nloc + wn + j * 16 + l15], cs[j]);
    }
}

// K3: E = exp(c*q@k^T - beta_j) e4m3, l += rowsum(E)
__global__ __launch_bounds__(256, 2) void k_score(
        const char* __restrict__ q8, const char* __restrict__ k8,
        char* __restrict__ E, float* __restrict__ l, const float* __restrict__ cptr,
        const float* __restrict__ beta) {
    __shared__ __align__(16) char smem[32768];
    int bm, bn; tile_coords(blockIdx.x, 64, bm, bn);
    int m0 = bm * 128, n0 = bn * 128;
    v4f acc[4][4];
    gemm_core_fp8(q8, k8, DD, m0, n0, smem, acc);

    const float cv = cptr[0];
    const int tid = threadIdx.x, wave = tid >> 6, lane = tid & 63;
    const int l15 = lane & 15, l4 = lane >> 4;
    const int wm = (wave >> 1) << 6, wn = (wave & 1) << 6;
    float bj[4];
#pragma unroll
    for (int j = 0; j < 4; j++) bj[j] = beta[n0 + wn + j * 16 + l15];
#pragma unroll
    for (int i = 0; i < 4; i++)
#pragma unroll
        for (int v = 0; v < 4; v++) {
            int row = m0 + wm + i * 16 + l4 * 4 + v;
            float rsum = 0.f;
#pragma unroll
            for (int j = 0; j < 4; j++) {
                float e = __expf(cv * acc[i][j][v] - bj[j]);
                E[(size_t)row * NT + (n0 + wn + j * 16 + l15)] = f2e4m3(e);
                rsum += e;
            }
#pragma unroll
            for (int o = 1; o < 16; o <<= 1) rsum += __shfl_xor(rsum, o);
            if (l15 == 0) atomicAdd(&l[row], rsum);
        }
}

// K4: out = (E @ g)/l + (em/gden)*gsum + x
__global__ __launch_bounds__(256, 2) void k_out(
        const char* __restrict__ E, const char* __restrict__ gbt,
        const float* __restrict__ l, const float* __restrict__ em,
        const float* __restrict__ gden, const float* __restrict__ gsum,
        const float* __restrict__ x, float* __restrict__ out) {
    __shared__ __align__(16) char smem[32768];
    int bm, bn; tile_coords(blockIdx.x, 8, bm, bn);
    int m0 = bm * 128, n0 = bn * 128;
    v4f acc[4][4];
    gemm_core_mx(E, gbt, NT, m0, n0, smem, acc);

    const float ginv = 1.f / gden[0];
    const int tid = threadIdx.x, wave = tid >> 6, lane = tid & 63;
    const int l15 = lane & 15, l4 = lane >> 4;
    const int wm = (wave >> 1) << 6, wn = (wave & 1) << 6;
#pragma unroll
    for (int i = 0; i < 4; i++)
#pragma unroll
        for (int v = 0; v < 4; v++) {
            int row = m0 + wm + i * 16 + l4 * 4 + v;
            float inv = 1.f / l[row];
            float gv  = em[row] * ginv;
#pragma unroll
            for (int j = 0; j < 4; j++) {
                int col = n0 + wn + j * 16 + l15;
                out[(size_t)row * DD + col] =
                    acc[i][j][v] * inv + gv * gsum[col] + x[(size_t)row * DD + col];
            }
        }
}

// ---------------- launch ----------------

extern "C" void kernel_launch(void* const* d_in, const int* in_sizes, int n_in,
                              void* d_out, int out_size, void* d_ws, size_t ws_size,
                              hipStream_t stream) {
    const float* x  = (const float*)d_in[0];
    const float* Wq = (const float*)d_in[1];
    const float* Wk = (const float*)d_in[2];
    const float* Wg = (const float*)d_in[3];
    const float* Wm = (const float*)d_in[4];
    const float* Wb = (const float*)d_in[5];
    const float* cp = (const float*)d_in[6];
    float* out = (float*)d_out;

    char* w = (char*)d_ws;
    size_t off = 0;
    auto alloc = [&](size_t bytes) -> void* {
        void* p = w + off;
        off += (bytes + 255) & ~(size_t)255;
        return p;
    };
    char*  q8    = (char*)alloc((size_t)NT * DD);           // 8 MB fp8 q_hat
    char*  k8    = (char*)alloc((size_t)NT * DD);           // 8 MB fp8 k_hat
    char*  gbt   = (char*)alloc((size_t)DD * NT);           // 8 MB fp8 g^T
    short* wbt   = (short*)alloc((size_t)3 * DD * DD * 2);  // 6 MB
    short* xb    = (short*)alloc((size_t)NT * DD * 2);      // 16 MB
    char*  E     = (char*)alloc((size_t)NT * NT);           // 64 MB fp8
    float* stats = (float*)alloc((2 * DD + 3 * NT + 1) * 4);
    float* qsum = stats;
    float* gsum = stats + DD;
    float* lrow = stats + 2 * DD;
    float* gden = lrow + NT;               // zeroed region: [stats, gden] inclusive
    float* em   = gden + 1;
    float* beta = em + NT;
    if (off > ws_size) return;

    hipMemsetAsync(stats, 0, (size_t)(2 * DD + NT + 1) * 4, stream);

    x_prep<<<NT / 4, 256, 0, stream>>>(x, Wm, Wb, xb, em, gden);
    cvt_w<<<dim3(16, 16, 3), 256, 0, stream>>>(Wq, Wk, Wg, wbt);
    k_proj<<<64 * 24, 256, 0, stream>>>(xb, wbt, q8, k8, gbt, qsum, gsum);
    beta_gemv<<<NT / 4, 256, 0, stream>>>(k8, qsum, cp, beta);
    k_score<<<64 * 64, 256, 0, stream>>>(q8, k8, E, lrow, cp, beta);
    k_out<<<64 * 8, 256, 0, stream>>>(E, gbt, lrow, em, gden, gsum, x, out);
}